// Round 10
// baseline (6675.085 us; speedup 1.0000x reference)
//
#include <hip/hip_runtime.h>

typedef unsigned short u16;
typedef unsigned int u32;

#define TB 64   // one sample per thread, one wave per block

// ---- graph constants copied verbatim from the reference ----
__device__ static constexpr int PRED[6][2] = {{0,3},{1,5},{0,4},{2,7},{1,6},{2,8}};
__device__ static constexpr int EDG [6][2] = {{0,1},{0,2},{1,0},{1,2},{2,0},{2,1}};
__device__ static constexpr int INCM[3][2] = {{2,4},{0,5},{1,3}};

// ALL inputs f32 (proven r7/r8); output f32 (proven r9: err0 passed with f32 writes)
struct WPtrs { const float* p[32]; };

// LDS row layout (per-thread column): L[row*TB + tid]
#define R_IN  0
#define R_MPH 68
#define R_EF  260
#define R_T   356
#define NROW  420   // 420*64*4 = 107520 B dynamic LDS

extern "C" __global__ void __launch_bounds__(TB, 1)
critic_mech(const float* __restrict__ obs, const float* __restrict__ act,
            const float* __restrict__ ag, const float* __restrict__ g,
            WPtrs wp, float* __restrict__ out, int B)
{
  extern __shared__ float L[];
  const int tid = threadIdx.x;
  const int s = blockIdx.x*TB + tid;
  if (s >= B) return;
  #define LDR(r) L[(r)*TB + tid]

  // ---- stage inputs (f32) ----
  for(int k=0;k<4;k++)  LDR(k)      = act[s*4+k];
  for(int k=0;k<55;k++) LDR(4+k)    = obs[s*55+k];
  for(int k=0;k<9;k++)  LDR(59+k)   = g[s*9+k] - ag[s*9+k];

  // ---- MP: out_mp[e] = mlp2(inp_mp[e]) ----
  {
    const float* W1=wp.p[0]; const float* B1=wp.p[1];
    const float* W2=wp.p[2]; const float* B2=wp.p[3];
    for(int e=0;e<6;e++){
      float xin[8];
      #pragma unroll
      for(int i=0;i<2;i++) xin[i]   = LDR(59 + PRED[e][i]);
      #pragma unroll
      for(int i=0;i<3;i++) xin[2+i] = LDR(4 + 10 + 15*EDG[e][0] + i);
      #pragma unroll
      for(int i=0;i<3;i++) xin[5+i] = LDR(4 + 10 + 15*EDG[e][1] + i);
      float o32[32];
      #pragma unroll
      for(int m=0;m<32;m++) o32[m]=B2[m];
      for(int c=0;c<4;c++){
        float hh[64];
        #pragma unroll
        for(int n=0;n<64;n++) hh[n]=B1[c*64+n];
        #pragma unroll
        for(int k=0;k<8;k++){
          const float* w = W1 + k*256 + c*64;
          #pragma unroll
          for(int n=0;n<64;n++) hh[n]=fmaf(xin[k],w[n],hh[n]);
        }
        #pragma unroll
        for(int n=0;n<64;n++) LDR(R_T+n)=fmaxf(hh[n],0.f);
        for(int n=0;n<64;n++){
          float hv=LDR(R_T+n);
          const float* w = W2 + (c*64+n)*32;
          #pragma unroll
          for(int m=0;m<32;m++) o32[m]=fmaf(hv,w[m],o32[m]);
        }
      }
      #pragma unroll
      for(int m=0;m<32;m++) LDR(R_MPH+e*32+m)=o32[m];
    }
  }

  // ---- EA per object: literal 2-token self-attn, then sum over s ----
  for(int o=0;o<3;o++){
    float x0[32], x1[32];
    #pragma unroll
    for(int k=0;k<32;k++){
      x0[k]=LDR(R_MPH+INCM[o][0]*32+k);
      x1[k]=LDR(R_MPH+INCM[o][1]*32+k);
    }
    float q0=wp.p[5][0], q1=wp.p[5][0], k0=wp.p[7][0], k1=wp.p[7][0];
    #pragma unroll
    for(int k=0;k<32;k++){
      q0=fmaf(x0[k],wp.p[4][k],q0); q1=fmaf(x1[k],wp.p[4][k],q1);
      k0=fmaf(x0[k],wp.p[6][k],k0); k1=fmaf(x1[k],wp.p[6][k],k1);
    }
    float v0[32], v1[32];
    #pragma unroll
    for(int n=0;n<32;n++){ float bv=wp.p[9][n]; v0[n]=bv; v1[n]=bv; }
    #pragma unroll
    for(int k=0;k<32;k++){
      const float* w = wp.p[8] + k*32;
      #pragma unroll
      for(int n=0;n<32;n++){ v0[n]=fmaf(x0[k],w[n],v0[n]); v1[n]=fmaf(x1[k],w[n],v1[n]); }
    }
    float s00=q0*k0, s01=q0*k1, s10=q1*k0, s11=q1*k1;
    float m0=fmaxf(s00,s01), m1=fmaxf(s10,s11);
    float e00=expf(s00-m0), e01=expf(s01-m0), e10=expf(s10-m1), e11=expf(s11-m1);
    float d0=e00+e01, d1=e10+e11;
    float a00=e00/d0, a01=e01/d0, a10=e10/d1, a11=e11/d1;
    #pragma unroll
    for(int n=0;n<32;n++){
      float row0 = a00*v0[n] + a01*v1[n];
      float row1 = a10*v0[n] + a11*v1[n];
      LDR(R_EF+o*32+n) = row0 + row1;   // sum over s
    }
  }

  // ---- two heads ----
  for(int set=0; set<2; set++){
    const float* pw1=wp.p[set?14:10]; const float* pb1=wp.p[set?15:11];
    const float* pw2=wp.p[set?16:12]; const float* pb2=wp.p[set?17:13];

    for(int j=0;j<3;j++){
      float o64[64];
      #pragma unroll
      for(int n=0;n<64;n++) o64[n]=pb2[n];
      for(int c=0;c<4;c++){
        float hh[64];
        #pragma unroll
        for(int n=0;n<64;n++) hh[n]=pb1[c*64+n];
        for(int k=0;k<61;k++){
          int row = (k<14) ? k : (k<29) ? (4+10+15*j+(k-14)) : (R_EF+32*j+(k-29));
          float xv = LDR(row);
          const float* w = pw1 + k*256 + c*64;
          #pragma unroll
          for(int n=0;n<64;n++) hh[n]=fmaf(xv,w[n],hh[n]);
        }
        #pragma unroll
        for(int n=0;n<64;n++) LDR(R_T+n)=fmaxf(hh[n],0.f);
        for(int n=0;n<64;n++){
          float hv=LDR(R_T+n);
          const float* w = pw2 + (c*64+n)*64;
          #pragma unroll
          for(int m=0;m<64;m++) o64[m]=fmaf(hv,w[m],o64[m]);
        }
      }
      #pragma unroll
      for(int n=0;n<64;n++) LDR(R_MPH+j*64+n)=fmaxf(o64[n],0.f);   // relu_out; h token j
    }

    // NA: literal 3-token self-attn over h tokens, then sum over s
    float qn[3], kn[3];
    #pragma unroll
    for(int j=0;j<3;j++){
      float qq=wp.p[19][0], kk=wp.p[21][0];
      for(int n=0;n<64;n++){
        float hv=LDR(R_MPH+j*64+n);
        qq=fmaf(hv,wp.p[18][n],qq);
        kk=fmaf(hv,wp.p[20][n],kk);
      }
      qn[j]=qq; kn[j]=kk;
    }
    float a[3][3];
    #pragma unroll
    for(int i=0;i<3;i++){
      float t0=qn[i]*kn[0], t1=qn[i]*kn[1], t2=qn[i]*kn[2];
      float mm=fmaxf(fmaxf(t0,t1),t2);
      float e0=expf(t0-mm), e1=expf(t1-mm), e2=expf(t2-mm);
      float dd=e0+e1+e2;
      a[i][0]=e0/dd; a[i][1]=e1/dd; a[i][2]=e2/dd;
    }
    float acc[3][64];
    #pragma unroll
    for(int ss2=0;ss2<3;ss2++)
      #pragma unroll
      for(int n=0;n<64;n++) acc[ss2][n]=0.f;
    #pragma unroll
    for(int t=0;t<3;t++){
      float v[64];
      #pragma unroll
      for(int n=0;n<64;n++) v[n]=wp.p[23][n];
      for(int k=0;k<64;k++){
        float hv=LDR(R_MPH+t*64+k);
        const float* w = wp.p[22] + k*64;
        #pragma unroll
        for(int n=0;n<64;n++) v[n]=fmaf(hv,w[n],v[n]);
      }
      #pragma unroll
      for(int ss2=0;ss2<3;ss2++)
        #pragma unroll
        for(int n=0;n<64;n++) acc[ss2][n]=fmaf(a[ss2][t],v[n],acc[ss2][n]);
    }
    #pragma unroll
    for(int n=0;n<64;n++) LDR(R_T+n)=acc[0][n]+acc[1][n]+acc[2][n];

    // rho: 64 -> 256 relu -> 1
    const float* rw1=wp.p[set?28:24]; const float* rb1=wp.p[set?29:25];
    const float* rw2=wp.p[set?30:26];
    float qacc = wp.p[set?31:27][0];
    for(int c=0;c<4;c++){
      float hh[64];
      #pragma unroll
      for(int n=0;n<64;n++) hh[n]=rb1[c*64+n];
      for(int k=0;k<64;k++){
        float sv=LDR(R_T+k);
        const float* w = rw1 + k*256 + c*64;
        #pragma unroll
        for(int n=0;n<64;n++) hh[n]=fmaf(sv,w[n],hh[n]);
      }
      #pragma unroll
      for(int n=0;n<64;n++) qacc=fmaf(fmaxf(hh[n],0.f),rw2[c*64+n],qacc);
    }
    out[set*B + s] = qacc;   // f32 output, slot order (q1, q2)
  }
  #undef LDR
}

// sentinel: fill output with a recognizable value (f32)
extern "C" __global__ void sentinel_fill(float* out, int n, float val){
  int i = blockIdx.x*blockDim.x + threadIdx.x;
  for(; i<n; i += gridDim.x*blockDim.x) out[i] = val;
}

extern "C" void kernel_launch(void* const* d_in, const int* in_sizes, int n_in,
                              void* d_out, int out_size, void* d_ws, size_t ws_size,
                              hipStream_t stream) {
  float* out = (float*)d_out;

  if (n_in != 36) {
    hipLaunchKernelGGL(sentinel_fill, dim3(256), dim3(256), 0, stream, out, out_size, 9000.0f);
    return;
  }
  if (in_sizes[0] % 55 != 0) {
    hipLaunchKernelGGL(sentinel_fill, dim3(256), dim3(256), 0, stream, out, out_size, 8888.0f);
    return;
  }
  const int B = in_sizes[0] / 55;
  if (out_size != 2*B) {
    hipLaunchKernelGGL(sentinel_fill, dim3(256), dim3(256), 0, stream, out, out_size, 7777.0f);
    return;
  }

  const float* obs = (const float*)d_in[0];
  const float* act = (const float*)d_in[1];
  const float* ag  = (const float*)d_in[2];
  const float* g   = (const float*)d_in[3];
  WPtrs wp;
  for(int i=0;i<32;i++) wp.p[i] = (const float*)d_in[4+i];

  const size_t lds_bytes = (size_t)NROW * TB * sizeof(float);   // 107520
  dim3 grid((B + TB - 1)/TB), block(TB);
  hipLaunchKernelGGL(critic_mech, grid, block, lds_bytes, stream,
                     obs, act, ag, g, wp, out, B);
}

// Round 11
// 2892.083 us; speedup vs baseline: 2.3081x; 2.3081x over previous
//
#include <hip/hip_runtime.h>

typedef unsigned short u16;
typedef unsigned int u32;

#define TB 64

// ---- graph constants (verbatim from reference) ----
__device__ static constexpr int PRED[6][2] = {{0,3},{1,5},{0,4},{2,7},{1,6},{2,8}};
__device__ static constexpr int EDG [6][2] = {{0,1},{0,2},{1,0},{1,2},{2,0},{2,1}};
__device__ static constexpr int INCM[3][2] = {{2,4},{0,5},{1,3}};

struct WPtrs { const float* p[32]; };

// ws layout (floats): ef [3][32][B] @0 ; h [6][64][B] @96B ; qk [6][2][B] @480B ; total 492*B

// =====================================================================
// Pass A: edge MLPs + edge attention -> ef
// LDS rows: 0..8 dg, 9..17 obj[:,:3], 18..81 hh scratch  (82 rows = 21 KB)
// =====================================================================
extern "C" __global__ void __launch_bounds__(TB, 2)
pass_ef(const float* __restrict__ obs, const float* __restrict__ ag,
        const float* __restrict__ g, WPtrs wp, float* __restrict__ ws, int B)
{
  __shared__ float L[82*TB];
  const int tid = threadIdx.x;
  const int s = blockIdx.x*TB + tid;
  if (s >= B) return;
  #define LDR(r) L[(r)*TB + tid]

  #pragma unroll
  for(int k=0;k<9;k++) LDR(k) = g[s*9+k] - ag[s*9+k];
  #pragma unroll
  for(int o=0;o<3;o++)
    #pragma unroll
    for(int i=0;i<3;i++) LDR(9+o*3+i) = obs[s*55+10+15*o+i];

  const float* W1=wp.p[0]; const float* B1=wp.p[1];
  const float* W2=wp.p[2]; const float* B2=wp.p[3];
  float* ef = ws;

  #pragma unroll
  for(int o=0;o<3;o++){
    float v0[32], v1[32];
    float q0,k0,q1,k1;
    #pragma unroll
    for(int slot=0;slot<2;slot++){
      const int e = INCM[o][slot];
      // ---- mp MLP: 8 -> 256 relu -> 32 ----
      float o32[32];
      #pragma unroll
      for(int m=0;m<32;m++) o32[m]=B2[m];
      #pragma unroll 1
      for(int c=0;c<4;c++){
        float hh[64];
        #pragma unroll
        for(int n=0;n<64;n++) hh[n]=B1[c*64+n];
        #pragma unroll
        for(int k=0;k<8;k++){
          const int row = (k<2) ? PRED[e][k] : (k<5) ? (9+3*EDG[e][0]+(k-2)) : (9+3*EDG[e][1]+(k-5));
          float xv = LDR(row);
          const float* w = W1 + k*256 + c*64;
          #pragma unroll
          for(int n=0;n<64;n++) hh[n]=fmaf(xv,w[n],hh[n]);
        }
        #pragma unroll
        for(int n=0;n<64;n++) LDR(18+n)=fmaxf(hh[n],0.f);
        #pragma unroll 1
        for(int n=0;n<64;n++){
          float hv=LDR(18+n);
          const float* w = W2 + (c*64+n)*32;
          #pragma unroll
          for(int m=0;m<32;m++) o32[m]=fmaf(hv,w[m],o32[m]);
        }
      }
      // ---- per-token q,k,v from o32 (x_t) ----
      float qt=wp.p[5][0], kt=wp.p[7][0];
      #pragma unroll
      for(int k=0;k<32;k++){ qt=fmaf(o32[k],wp.p[4][k],qt); kt=fmaf(o32[k],wp.p[6][k],kt); }
      float vt[32];
      #pragma unroll
      for(int n=0;n<32;n++) vt[n]=wp.p[9][n];
      #pragma unroll
      for(int k=0;k<32;k++){
        const float* w = wp.p[8] + k*32;
        #pragma unroll
        for(int n=0;n<32;n++) vt[n]=fmaf(o32[k],w[n],vt[n]);
      }
      if(slot==0){ q0=qt; k0=kt;
        #pragma unroll
        for(int n=0;n<32;n++) v0[n]=vt[n];
      } else { q1=qt; k1=kt;
        #pragma unroll
        for(int n=0;n<32;n++) v1[n]=vt[n];
      }
    }
    // 2x2 softmax over keys, summed over queries
    float s00=q0*k0, s01=q0*k1, s10=q1*k0, s11=q1*k1;
    float m0=fmaxf(s00,s01), m1=fmaxf(s10,s11);
    float e00=expf(s00-m0), e01=expf(s01-m0), e10=expf(s10-m1), e11=expf(s11-m1);
    float d0=e00+e01, d1=e10+e11;
    float c0=e00/d0+e10/d1, c1=e01/d0+e11/d1;
    #pragma unroll
    for(int n=0;n<32;n++) ef[(o*32+n)*B + s] = fmaf(c0,v0[n], c1*v1[n]);
  }
  #undef LDR
}

// =====================================================================
// Pass B1: phi MLP per (set,j) -> h tokens + na q,k scalars
// blockIdx.y = combo (0..5), set=combo/3, j=combo%3
// LDS rows: 0..60 xin, 61..124 hh  (125 rows = 32 KB)
// =====================================================================
extern "C" __global__ void __launch_bounds__(TB, 2)
pass_phi(const float* __restrict__ obs, const float* __restrict__ act,
         WPtrs wp, float* __restrict__ ws, int B)
{
  __shared__ float L[125*TB];
  const int tid = threadIdx.x;
  const int s = blockIdx.x*TB + tid;
  if (s >= B) return;
  const int combo = blockIdx.y;
  const int set = combo/3, j = combo%3;
  #define LDR(r) L[(r)*TB + tid]

  const float* ef = ws;
  float* h  = ws + 96*B;
  float* qk = ws + 480*B;

  // stage xin[61]
  #pragma unroll
  for(int k=0;k<4;k++)  LDR(k)    = act[s*4+k];
  #pragma unroll
  for(int k=0;k<10;k++) LDR(4+k)  = obs[s*55+k];
  #pragma unroll
  for(int k=0;k<15;k++) LDR(14+k) = obs[s*55+10+15*j+k];
  #pragma unroll
  for(int k=0;k<32;k++) LDR(29+k) = ef[(j*32+k)*B + s];

  const float* pw1 = wp.p[set?14:10]; const float* pb1 = wp.p[set?15:11];
  const float* pw2 = wp.p[set?16:12]; const float* pb2 = wp.p[set?17:13];

  float o64[64];
  #pragma unroll
  for(int n=0;n<64;n++) o64[n]=pb2[n];

  #pragma unroll 1
  for(int c=0;c<4;c++){
    float hh[64];
    #pragma unroll
    for(int n=0;n<64;n++) hh[n]=pb1[c*64+n];
    #pragma unroll 1
    for(int k=0;k<61;k++){
      float xv = LDR(k);
      const float* w = pw1 + k*256 + c*64;
      #pragma unroll
      for(int n=0;n<64;n++) hh[n]=fmaf(xv,w[n],hh[n]);
    }
    #pragma unroll
    for(int n=0;n<64;n++) LDR(61+n)=fmaxf(hh[n],0.f);
    #pragma unroll 1
    for(int n=0;n<64;n++){
      float hv=LDR(61+n);
      const float* w = pw2 + (c*64+n)*64;
      #pragma unroll
      for(int m=0;m<64;m++) o64[m]=fmaf(hv,w[m],o64[m]);
    }
  }

  // relu_out, write h, na q/k scalars
  float qj=wp.p[19][0], kj=wp.p[21][0];
  #pragma unroll
  for(int n=0;n<64;n++){
    float hv = fmaxf(o64[n],0.f);
    h[(combo*64+n)*B + s] = hv;
    qj = fmaf(hv, wp.p[18][n], qj);
    kj = fmaf(hv, wp.p[20][n], kj);
  }
  qk[(combo*2+0)*B + s] = qj;
  qk[(combo*2+1)*B + s] = kj;
  #undef LDR
}

// =====================================================================
// Pass B2: na attention (column-sum hoist, exact) + rho -> out
// blockIdx.y = set. LDS rows: 0..63 t64, 64..127 s64  (128 rows = 32.7 KB)
// =====================================================================
extern "C" __global__ void __launch_bounds__(TB, 2)
pass_rho(WPtrs wp, const float* __restrict__ ws, float* __restrict__ out, int B)
{
  __shared__ float L[128*TB];
  const int tid = threadIdx.x;
  const int s = blockIdx.x*TB + tid;
  if (s >= B) return;
  const int set = blockIdx.y;
  #define LDR(r) L[(r)*TB + tid]

  const float* h  = ws + 96*B;
  const float* qk = ws + 480*B;

  float qn[3], kn[3];
  #pragma unroll
  for(int t=0;t<3;t++){
    qn[t] = qk[((set*3+t)*2+0)*B + s];
    kn[t] = qk[((set*3+t)*2+1)*B + s];
  }
  float cw0=0.f, cw1=0.f, cw2=0.f;
  #pragma unroll
  for(int i=0;i<3;i++){
    float t0=qn[i]*kn[0], t1=qn[i]*kn[1], t2=qn[i]*kn[2];
    float mm=fmaxf(fmaxf(t0,t1),t2);
    float e0=expf(t0-mm), e1=expf(t1-mm), e2=expf(t2-mm);
    float dd=e0+e1+e2;
    cw0 += e0/dd; cw1 += e1/dd; cw2 += e2/dd;
  }

  // t64 = cw0*h0 + cw1*h1 + cw2*h2  (streamed, coalesced)
  #pragma unroll
  for(int n=0;n<64;n++){
    float t = cw0*h[((set*3+0)*64+n)*B+s]
            + cw1*h[((set*3+1)*64+n)*B+s]
            + cw2*h[((set*3+2)*64+n)*B+s];
    LDR(n) = t;
  }
  // s64 = t64 @ naWv + 3*nabv
  float s64[64];
  #pragma unroll
  for(int n=0;n<64;n++) s64[n] = 3.f*wp.p[23][n];
  #pragma unroll 1
  for(int k=0;k<64;k++){
    float tv = LDR(k);
    const float* w = wp.p[22] + k*64;
    #pragma unroll
    for(int n=0;n<64;n++) s64[n]=fmaf(tv,w[n],s64[n]);
  }
  #pragma unroll
  for(int n=0;n<64;n++) LDR(64+n)=s64[n];

  // rho: 64 -> 256 relu -> 1
  const float* rw1=wp.p[set?28:24]; const float* rb1=wp.p[set?29:25];
  const float* rw2=wp.p[set?30:26];
  float qacc = wp.p[set?31:27][0];
  #pragma unroll 1
  for(int c=0;c<4;c++){
    float hh[64];
    #pragma unroll
    for(int n=0;n<64;n++) hh[n]=rb1[c*64+n];
    #pragma unroll 1
    for(int k=0;k<64;k++){
      float sv=LDR(64+k);
      const float* w = rw1 + k*256 + c*64;
      #pragma unroll
      for(int n=0;n<64;n++) hh[n]=fmaf(sv,w[n],hh[n]);
    }
    #pragma unroll
    for(int n=0;n<64;n++) qacc=fmaf(fmaxf(hh[n],0.f),rw2[c*64+n],qacc);
  }
  out[set*B + s] = qacc;
  #undef LDR
}

// =====================================================================
// Fallback: round-10 monolithic kernel (proven correct) if ws too small
// =====================================================================
#define R_MPH 68
#define R_EF  260
#define R_T   356
#define NROW  420

extern "C" __global__ void __launch_bounds__(TB, 1)
critic_mech(const float* __restrict__ obs, const float* __restrict__ act,
            const float* __restrict__ ag, const float* __restrict__ g,
            WPtrs wp, float* __restrict__ out, int B)
{
  extern __shared__ float L[];
  const int tid = threadIdx.x;
  const int s = blockIdx.x*TB + tid;
  if (s >= B) return;
  #define LDR(r) L[(r)*TB + tid]
  for(int k=0;k<4;k++)  LDR(k)      = act[s*4+k];
  for(int k=0;k<55;k++) LDR(4+k)    = obs[s*55+k];
  for(int k=0;k<9;k++)  LDR(59+k)   = g[s*9+k] - ag[s*9+k];
  {
    const float* W1=wp.p[0]; const float* B1=wp.p[1];
    const float* W2=wp.p[2]; const float* B2=wp.p[3];
    for(int e=0;e<6;e++){
      float xin[8];
      #pragma unroll
      for(int i=0;i<2;i++) xin[i]   = LDR(59 + PRED[e][i]);
      #pragma unroll
      for(int i=0;i<3;i++) xin[2+i] = LDR(4 + 10 + 15*EDG[e][0] + i);
      #pragma unroll
      for(int i=0;i<3;i++) xin[5+i] = LDR(4 + 10 + 15*EDG[e][1] + i);
      float o32[32];
      #pragma unroll
      for(int m=0;m<32;m++) o32[m]=B2[m];
      for(int c=0;c<4;c++){
        float hh[64];
        #pragma unroll
        for(int n=0;n<64;n++) hh[n]=B1[c*64+n];
        #pragma unroll
        for(int k=0;k<8;k++){
          const float* w = W1 + k*256 + c*64;
          #pragma unroll
          for(int n=0;n<64;n++) hh[n]=fmaf(xin[k],w[n],hh[n]);
        }
        #pragma unroll
        for(int n=0;n<64;n++) LDR(R_T+n)=fmaxf(hh[n],0.f);
        for(int n=0;n<64;n++){
          float hv=LDR(R_T+n);
          const float* w = W2 + (c*64+n)*32;
          #pragma unroll
          for(int m=0;m<32;m++) o32[m]=fmaf(hv,w[m],o32[m]);
        }
      }
      #pragma unroll
      for(int m=0;m<32;m++) LDR(R_MPH+e*32+m)=o32[m];
    }
  }
  for(int o=0;o<3;o++){
    float x0[32], x1[32];
    #pragma unroll
    for(int k=0;k<32;k++){
      x0[k]=LDR(R_MPH+INCM[o][0]*32+k);
      x1[k]=LDR(R_MPH+INCM[o][1]*32+k);
    }
    float q0=wp.p[5][0], q1=wp.p[5][0], k0=wp.p[7][0], k1=wp.p[7][0];
    #pragma unroll
    for(int k=0;k<32;k++){
      q0=fmaf(x0[k],wp.p[4][k],q0); q1=fmaf(x1[k],wp.p[4][k],q1);
      k0=fmaf(x0[k],wp.p[6][k],k0); k1=fmaf(x1[k],wp.p[6][k],k1);
    }
    float v0[32], v1[32];
    #pragma unroll
    for(int n=0;n<32;n++){ v0[n]=wp.p[9][n]; v1[n]=wp.p[9][n]; }
    #pragma unroll
    for(int k=0;k<32;k++){
      const float* w = wp.p[8] + k*32;
      #pragma unroll
      for(int n=0;n<32;n++){ v0[n]=fmaf(x0[k],w[n],v0[n]); v1[n]=fmaf(x1[k],w[n],v1[n]); }
    }
    float s00=q0*k0, s01=q0*k1, s10=q1*k0, s11=q1*k1;
    float m0=fmaxf(s00,s01), m1=fmaxf(s10,s11);
    float e00=expf(s00-m0), e01=expf(s01-m0), e10=expf(s10-m1), e11=expf(s11-m1);
    float d0=e00+e01, d1=e10+e11;
    float a00=e00/d0, a01=e01/d0, a10=e10/d1, a11=e11/d1;
    #pragma unroll
    for(int n=0;n<32;n++)
      LDR(R_EF+o*32+n) = (a00*v0[n]+a01*v1[n]) + (a10*v0[n]+a11*v1[n]);
  }
  for(int set=0; set<2; set++){
    const float* pw1=wp.p[set?14:10]; const float* pb1=wp.p[set?15:11];
    const float* pw2=wp.p[set?16:12]; const float* pb2=wp.p[set?17:13];
    for(int j=0;j<3;j++){
      float o64[64];
      #pragma unroll
      for(int n=0;n<64;n++) o64[n]=pb2[n];
      for(int c=0;c<4;c++){
        float hh[64];
        #pragma unroll
        for(int n=0;n<64;n++) hh[n]=pb1[c*64+n];
        for(int k=0;k<61;k++){
          int row = (k<14) ? k : (k<29) ? (4+10+15*j+(k-14)) : (R_EF+32*j+(k-29));
          float xv = LDR(row);
          const float* w = pw1 + k*256 + c*64;
          #pragma unroll
          for(int n=0;n<64;n++) hh[n]=fmaf(xv,w[n],hh[n]);
        }
        #pragma unroll
        for(int n=0;n<64;n++) LDR(R_T+n)=fmaxf(hh[n],0.f);
        for(int n=0;n<64;n++){
          float hv=LDR(R_T+n);
          const float* w = pw2 + (c*64+n)*64;
          #pragma unroll
          for(int m=0;m<64;m++) o64[m]=fmaf(hv,w[m],o64[m]);
        }
      }
      #pragma unroll
      for(int n=0;n<64;n++) LDR(R_MPH+j*64+n)=fmaxf(o64[n],0.f);
    }
    float qn[3], kn[3];
    #pragma unroll
    for(int j=0;j<3;j++){
      float qq=wp.p[19][0], kk=wp.p[21][0];
      for(int n=0;n<64;n++){
        float hv=LDR(R_MPH+j*64+n);
        qq=fmaf(hv,wp.p[18][n],qq);
        kk=fmaf(hv,wp.p[20][n],kk);
      }
      qn[j]=qq; kn[j]=kk;
    }
    float cw0=0.f,cw1=0.f,cw2=0.f;
    #pragma unroll
    for(int i=0;i<3;i++){
      float t0=qn[i]*kn[0], t1=qn[i]*kn[1], t2=qn[i]*kn[2];
      float mm=fmaxf(fmaxf(t0,t1),t2);
      float e0=expf(t0-mm), e1=expf(t1-mm), e2=expf(t2-mm);
      float dd=e0+e1+e2;
      cw0+=e0/dd; cw1+=e1/dd; cw2+=e2/dd;
    }
    #pragma unroll
    for(int n=0;n<64;n++)
      LDR(R_T+n) = cw0*LDR(R_MPH+0*64+n) + cw1*LDR(R_MPH+1*64+n) + cw2*LDR(R_MPH+2*64+n);
    float s64[64];
    #pragma unroll
    for(int n=0;n<64;n++) s64[n] = 3.f*wp.p[23][n];
    for(int k=0;k<64;k++){
      float xv = LDR(R_T+k);
      const float* w = wp.p[22] + k*64;
      #pragma unroll
      for(int n=0;n<64;n++) s64[n]=fmaf(xv,w[n],s64[n]);
    }
    #pragma unroll
    for(int n=0;n<64;n++) LDR(R_T+n)=s64[n];
    const float* rw1=wp.p[set?28:24]; const float* rb1=wp.p[set?29:25];
    const float* rw2=wp.p[set?30:26];
    float qacc = wp.p[set?31:27][0];
    for(int c=0;c<4;c++){
      float hh[64];
      #pragma unroll
      for(int n=0;n<64;n++) hh[n]=rb1[c*64+n];
      for(int k=0;k<64;k++){
        float sv=LDR(R_T+k);
        const float* w = rw1 + k*256 + c*64;
        #pragma unroll
        for(int n=0;n<64;n++) hh[n]=fmaf(sv,w[n],hh[n]);
      }
      #pragma unroll
      for(int n=0;n<64;n++) qacc=fmaf(fmaxf(hh[n],0.f),rw2[c*64+n],qacc);
    }
    out[set*B + s] = qacc;
  }
  #undef LDR
}

extern "C" __global__ void sentinel_fill(float* out, int n, float val){
  int i = blockIdx.x*blockDim.x + threadIdx.x;
  for(; i<n; i += gridDim.x*blockDim.x) out[i] = val;
}

extern "C" void kernel_launch(void* const* d_in, const int* in_sizes, int n_in,
                              void* d_out, int out_size, void* d_ws, size_t ws_size,
                              hipStream_t stream) {
  float* out = (float*)d_out;
  if (n_in != 36) { hipLaunchKernelGGL(sentinel_fill, dim3(256), dim3(256), 0, stream, out, out_size, 9000.0f); return; }
  const int B = in_sizes[0] / 55;
  if (out_size != 2*B) { hipLaunchKernelGGL(sentinel_fill, dim3(256), dim3(256), 0, stream, out, out_size, 7777.0f); return; }

  const float* obs = (const float*)d_in[0];
  const float* act = (const float*)d_in[1];
  const float* ag  = (const float*)d_in[2];
  const float* g   = (const float*)d_in[3];
  WPtrs wp;
  for(int i=0;i<32;i++) wp.p[i] = (const float*)d_in[4+i];

  const size_t ws_need = (size_t)492 * B * sizeof(float);
  const int nb = (B + TB - 1)/TB;

  if (ws_size >= ws_need) {
    float* ws = (float*)d_ws;
    hipLaunchKernelGGL(pass_ef,  dim3(nb),    dim3(TB), 0, stream, obs, ag, g, wp, ws, B);
    hipLaunchKernelGGL(pass_phi, dim3(nb, 6), dim3(TB), 0, stream, obs, act, wp, ws, B);
    hipLaunchKernelGGL(pass_rho, dim3(nb, 2), dim3(TB), 0, stream, wp, ws, out, B);
  } else {
    const size_t lds_bytes = (size_t)NROW * TB * sizeof(float);
    hipLaunchKernelGGL(critic_mech, dim3(nb), dim3(TB), lds_bytes, stream,
                       obs, act, ag, g, wp, out, B);
  }
}